// Round 10
// baseline (73.669 us; speedup 1.0000x reference)
//
#include <hip/hip_runtime.h>

#define TI 64     // tile edge
#define BT 256    // threads per block (4 waves)

// branchless bell; NaN (sentinel self-pair: 0*inf) fails ordered compares -> 0
__device__ __forceinline__ float bell(float d, float s) {
    float r  = d * __builtin_amdgcn_rcpf(s);
    float nr = fmaf(-2.0f * r, r, 1.0f);
    float t  = r - 1.0f;
    float fr = (t + t) * t;
    float p  = (r <= 0.5f) ? nr : fr;
    return (r <= 1.0f) ? p : 0.0f;
}

__device__ __forceinline__ float term(float4 P, float pai, float4 q) {
    float px = bell(fabsf(P.x - q.x), P.z + q.z);
    float py = bell(fabsf(P.y - q.y), P.w + q.w);
    return (pai + q.z * q.w) * px * py;     // quarter-area scale
}

__device__ __forceinline__ int tri_off(int ti, int T) {
    return ti * T - (ti * (ti - 1)) / 2;    // first block index of tile-row ti
}

__global__ __launch_bounds__(256) void prep_kernel(
    const float* __restrict__ pos,
    const float* __restrict__ msx, const float* __restrict__ msy,
    const float* __restrict__ bpx, const float* __restrict__ bpy,
    const int*   __restrict__ midx,
    int num_nodes, int m, int N, int Npad,
    float4* __restrict__ p4, float* __restrict__ T_accum)
{
    const int i = blockIdx.x * 256 + threadIdx.x;
    // macro_idx is int64 in the reference; sorted => idx[1] >= 1, so the odd
    // int32 words are all zero iff the buffer is little-endian int64.
    const bool is64 = (midx[1] == 0) && (midx[3] == 0) && (midx[5] == 0);
    float a = 0.0f, xi = 1e18f, yi = 1e18f, hx = 0.0f, hy = 0.0f;
    if (i < N) {
        hx = 0.5f * msx[i];
        hy = 0.5f * msy[i];
        if (i < m) {
            int id = is64 ? midx[2 * i] : midx[i];
            xi = pos[id]             + hx;
            yi = pos[num_nodes + id] + hy;
        } else {
            xi = bpx[i - m];
            yi = bpy[i - m];
        }
        a = 4.0f * hx * hy;                 // true area
    }
    if (i < Npad) p4[i] = make_float4(xi, yi, hx, hy);

    for (int off = 32; off > 0; off >>= 1) a += __shfl_down(a, off, 64);
    __shared__ float wpart[4];
    const int lane = threadIdx.x & 63, wid = threadIdx.x >> 6;
    if (lane == 0) wpart[wid] = a;
    __syncthreads();
    if (threadIdx.x == 0)
        atomicAdd(T_accum, wpart[0] + wpart[1] + wpart[2] + wpart[3]);
}

__global__ __launch_bounds__(BT) void pairs_kernel(
    const float4* __restrict__ p4, int T, int nblk,
    float* __restrict__ S_accum, float* __restrict__ T_accum,
    unsigned* __restrict__ done, float* __restrict__ out)
{
    // decode linear block id -> (ti, tj), ti <= tj
    const int b = blockIdx.x;
    const int w2 = 2 * T + 1;
    int ti = (int)(((float)w2 - sqrtf((float)(w2 * w2 - 8 * b))) * 0.5f);
    if (ti > T - 1) ti = T - 1;
    while (ti > 0 && tri_off(ti, T) > b) --ti;
    while (tri_off(ti + 1, T) <= b) ++ti;
    const int tj = ti + (b - tri_off(ti, T));

    __shared__ float4 qs[TI];
    if (threadIdx.x < TI) qs[threadIdx.x] = p4[tj * TI + threadIdx.x];
    __syncthreads();

    const int lane = threadIdx.x & 63, wid = threadIdx.x >> 6;
    const float4 P = p4[ti * TI + lane];    // coalesced, L2-hot
    const float pai = P.z * P.w;            // quarter-area

    float a0 = 0.0f, a1 = 0.0f;
    #pragma unroll
    for (int k = 0; k < 16; k += 2) {
        a0 += term(P, pai, qs[wid * 16 + k]);
        a1 += term(P, pai, qs[wid * 16 + k + 1]);
    }
    float part = a0 + a1;
    if (ti == tj) part *= 0.5f;             // diag tiles half-weight

    for (int off = 32; off > 0; off >>= 1) part += __shfl_down(part, off, 64);
    __shared__ float wsum[BT / 64];
    if (lane == 0) wsum[wid] = part;
    __syncthreads();

    if (threadIdx.x == 0) {
        atomicAdd(S_accum, wsum[0] + wsum[1] + wsum[2] + wsum[3]);
        __threadfence();
        unsigned old = atomicAdd(done, 1u);
        if (old == (unsigned)(nblk - 1)) {  // last block finalizes
            float S  = atomicAdd(S_accum, 0.0f);   // coherent read-back
            float Tt = atomicAdd(T_accum, 0.0f);
            // quarter-area scale: triu = 4*S - Tt
            float l = (4.0f * S - Tt) / Tt;
            out[0] = l * l;
        }
    }
}

extern "C" void kernel_launch(void* const* d_in, const int* in_sizes, int n_in,
                              void* d_out, int out_size, void* d_ws, size_t ws_size,
                              hipStream_t stream) {
    const float* pos = (const float*)d_in[0];
    const float* msx = (const float*)d_in[1];
    const float* msy = (const float*)d_in[2];
    const float* bpx = (const float*)d_in[3];
    const float* bpy = (const float*)d_in[4];
    const int*  midx = (const int*)d_in[5];

    const int num_nodes = in_sizes[0] / 2;
    const int m  = in_sizes[5];          // 4000 movable macros
    const int nb = in_sizes[3];          // 252 boundary nodes
    const int N  = m + nb;

    const int T     = (N + TI - 1) / TI;     // 68 tiles
    const int Npad  = T * TI;                // 4352
    const int nblk  = T * (T + 1) / 2;       // 2346 tile-pairs
    const int nprep = (Npad + 255) / 256;    // 17

    float*    S_accum = (float*)d_ws;        // [0]
    float*    T_accum = S_accum + 1;         // [1]
    unsigned* done    = (unsigned*)(S_accum + 2);
    float4*   p4      = (float4*)(S_accum + 4);

    hipMemsetAsync(d_ws, 0, 16, stream);     // zero S, T, done each call

    prep_kernel<<<nprep, 256, 0, stream>>>(pos, msx, msy, bpx, bpy, midx,
                                           num_nodes, m, N, Npad, p4, T_accum);

    pairs_kernel<<<nblk, BT, 0, stream>>>(p4, T, nblk,
                                          S_accum, T_accum, done,
                                          (float*)d_out);
}

// Round 11
// 28.006 us; speedup vs baseline: 2.6305x; 2.6305x over previous
//
#include <hip/hip_runtime.h>

#define TI 64     // tile edge
#define BT 256    // threads per pairs block (4 waves)

// branchless bell; NaN (sentinel self-pair: 0*inf) fails ordered compares -> 0
__device__ __forceinline__ float bell(float d, float s) {
    float r  = d * __builtin_amdgcn_rcpf(s);
    float nr = fmaf(-2.0f * r, r, 1.0f);
    float t  = r - 1.0f;
    float fr = (t + t) * t;
    float p  = (r <= 0.5f) ? nr : fr;
    return (r <= 1.0f) ? p : 0.0f;
}

__device__ __forceinline__ float term(float4 P, float pai, float4 q) {
    float px = bell(fabsf(P.x - q.x), P.z + q.z);
    float py = bell(fabsf(P.y - q.y), P.w + q.w);
    return (pai + q.z * q.w) * px * py;     // quarter-area scale
}

__device__ __forceinline__ int tri_off(int ti, int T) {
    return ti * T - (ti * (ti - 1)) / 2;    // first block index of tile-row ti
}

__global__ __launch_bounds__(256) void prep_kernel(
    const float* __restrict__ pos,
    const float* __restrict__ msx, const float* __restrict__ msy,
    const float* __restrict__ bpx, const float* __restrict__ bpy,
    const int*   __restrict__ midx,
    int num_nodes, int m, int N, int Npad,
    float4* __restrict__ p4, float* __restrict__ t_part)
{
    const int i = blockIdx.x * 256 + threadIdx.x;
    // macro_idx is int64 in the reference; sorted => idx[1] >= 1, so the odd
    // int32 words are all zero iff the buffer is little-endian int64.
    const bool is64 = (midx[1] == 0) && (midx[3] == 0) && (midx[5] == 0);
    float a = 0.0f, xi = 1e18f, yi = 1e18f, hx = 0.0f, hy = 0.0f;
    if (i < N) {
        hx = 0.5f * msx[i];
        hy = 0.5f * msy[i];
        if (i < m) {
            int id = is64 ? midx[2 * i] : midx[i];
            xi = pos[id]             + hx;
            yi = pos[num_nodes + id] + hy;
        } else {
            xi = bpx[i - m];
            yi = bpy[i - m];
        }
        a = 4.0f * hx * hy;                 // true area
    }
    if (i < Npad) p4[i] = make_float4(xi, yi, hx, hy);

    for (int off = 32; off > 0; off >>= 1) a += __shfl_down(a, off, 64);
    __shared__ float wpart[4];
    const int lane = threadIdx.x & 63, wid = threadIdx.x >> 6;
    if (lane == 0) wpart[wid] = a;
    __syncthreads();
    if (threadIdx.x == 0)
        t_part[blockIdx.x] = wpart[0] + wpart[1] + wpart[2] + wpart[3];
}

// LDS-free: j-nodes read via wave-uniform (scalar) loads, per-wave partials
__global__ __launch_bounds__(BT) void pairs_kernel(
    const float4* __restrict__ p4, int T, float* __restrict__ partials)
{
    // decode linear block id -> (ti, tj), ti <= tj
    const int b = blockIdx.x;
    const int w2 = 2 * T + 1;
    int ti = (int)(((float)w2 - sqrtf((float)(w2 * w2 - 8 * b))) * 0.5f);
    if (ti > T - 1) ti = T - 1;
    while (ti > 0 && tri_off(ti, T) > b) --ti;
    while (tri_off(ti + 1, T) <= b) ++ti;
    const int tj = ti + (b - tri_off(ti, T));

    const int lane = threadIdx.x & 63;
    // force wave-uniform wid into an SGPR so q addresses scalarize (s_load)
    const int wid = __builtin_amdgcn_readfirstlane((int)(threadIdx.x >> 6));

    const float4 P = p4[ti * TI + lane];    // coalesced, L2-hot
    const float pai = P.z * P.w;            // quarter-area

    const float4* qbase = p4 + tj * TI + wid * 16;   // wave-uniform base
    float a0 = 0.0f, a1 = 0.0f;
    #pragma unroll
    for (int k = 0; k < 16; k += 2) {
        float4 q0 = qbase[k];               // uniform -> scalar load
        float4 q1 = qbase[k + 1];
        a0 += term(P, pai, q0);
        a1 += term(P, pai, q1);
    }
    float part = a0 + a1;
    if (ti == tj) part *= 0.5f;             // diag tiles half-weight

    for (int off = 32; off > 0; off >>= 1) part += __shfl_down(part, off, 64);
    if (lane == 0) partials[b * 4 + wid] = part;     // per-wave partial
}

__global__ __launch_bounds__(256) void fin_kernel(
    const float* __restrict__ partials, int np,
    const float* __restrict__ t_part, int nt, float* __restrict__ out)
{
    float s = 0.0f;
    for (int i = threadIdx.x; i < np; i += 256) s += partials[i];
    float t = 0.0f;
    for (int i = threadIdx.x; i < nt; i += 256) t += t_part[i];
    for (int off = 32; off > 0; off >>= 1) {
        s += __shfl_down(s, off, 64);
        t += __shfl_down(t, off, 64);
    }
    __shared__ float ws[4], wt[4];
    const int lane = threadIdx.x & 63, wid = threadIdx.x >> 6;
    if (lane == 0) { ws[wid] = s; wt[wid] = t; }
    __syncthreads();
    if (threadIdx.x == 0) {
        float S = ws[0] + ws[1] + ws[2] + ws[3];
        float T = wt[0] + wt[1] + wt[2] + wt[3];
        // quarter-area scale: triu = 4*S - T
        float l = (4.0f * S - T) / T;
        out[0] = l * l;
    }
}

extern "C" void kernel_launch(void* const* d_in, const int* in_sizes, int n_in,
                              void* d_out, int out_size, void* d_ws, size_t ws_size,
                              hipStream_t stream) {
    const float* pos = (const float*)d_in[0];
    const float* msx = (const float*)d_in[1];
    const float* msy = (const float*)d_in[2];
    const float* bpx = (const float*)d_in[3];
    const float* bpy = (const float*)d_in[4];
    const int*  midx = (const int*)d_in[5];

    const int num_nodes = in_sizes[0] / 2;
    const int m  = in_sizes[5];          // 4000 movable macros
    const int nb = in_sizes[3];          // 252 boundary nodes
    const int N  = m + nb;

    const int T     = (N + TI - 1) / TI;     // 68 tiles
    const int Npad  = T * TI;                // 4352
    const int nblk  = T * (T + 1) / 2;       // 2346 tile-pairs
    const int nprep = (Npad + 255) / 256;    // 17

    float4* p4       = (float4*)d_ws;
    float*  t_part   = (float*)(p4 + Npad);
    float*  partials = t_part + nprep;       // 4 * nblk floats

    prep_kernel<<<nprep, 256, 0, stream>>>(pos, msx, msy, bpx, bpy, midx,
                                           num_nodes, m, N, Npad, p4, t_part);

    pairs_kernel<<<nblk, BT, 0, stream>>>(p4, T, partials);

    fin_kernel<<<1, 256, 0, stream>>>(partials, 4 * nblk, t_part, nprep,
                                      (float*)d_out);
}

// Round 13
// 24.945 us; speedup vs baseline: 2.9532x; 1.1227x over previous
//
#include <hip/hip_runtime.h>

#define TI 64     // i-tile edge
#define TJ 128    // j-extent per block (two 64-tiles)
#define BT 256    // threads per pairs block (4 waves)

// branchless bell; NaN (sentinel self-pair: 0*inf) fails ordered compares -> 0
__device__ __forceinline__ float bell(float d, float s) {
    float r  = d * __builtin_amdgcn_rcpf(s);
    float nr = fmaf(-2.0f * r, r, 1.0f);
    float t  = r - 1.0f;
    float fr = (t + t) * t;
    float p  = (r <= 0.5f) ? nr : fr;
    return (r <= 1.0f) ? p : 0.0f;
}

__device__ __forceinline__ float term(float4 P, float pai, float4 q) {
    float px = bell(fabsf(P.x - q.x), P.z + q.z);
    float py = bell(fabsf(P.y - q.y), P.w + q.w);
    return (pai + q.z * q.w) * px * py;     // quarter-area scale
}

// first block index of tile-row ti, for (ti, js) pairs with js >= ti/2
__host__ __device__ __forceinline__ int row_off(int ti, int Tj) {
    int f = (ti >= 1) ? ((ti - 1) * (ti - 1)) / 4 : 0;   // sum floor(t/2)
    return ti * Tj - f;
}

__global__ __launch_bounds__(256) void prep_kernel(
    const float* __restrict__ pos,
    const float* __restrict__ msx, const float* __restrict__ msy,
    const float* __restrict__ bpx, const float* __restrict__ bpy,
    const int*   __restrict__ midx,
    int num_nodes, int m, int N, int Npad,
    float4* __restrict__ p4, float* __restrict__ t_part)
{
    const int i = blockIdx.x * 256 + threadIdx.x;
    // macro_idx is int64 in the reference; sorted => idx[1] >= 1, so the odd
    // int32 words are all zero iff the buffer is little-endian int64.
    const bool is64 = (midx[1] == 0) && (midx[3] == 0) && (midx[5] == 0);
    float a = 0.0f, xi = 1e18f, yi = 1e18f, hx = 0.0f, hy = 0.0f;
    if (i < N) {
        hx = 0.5f * msx[i];
        hy = 0.5f * msy[i];
        if (i < m) {
            int id = is64 ? midx[2 * i] : midx[i];
            xi = pos[id]             + hx;
            yi = pos[num_nodes + id] + hy;
        } else {
            xi = bpx[i - m];
            yi = bpy[i - m];
        }
        a = 4.0f * hx * hy;                 // true area
    }
    if (i < Npad) p4[i] = make_float4(xi, yi, hx, hy);

    for (int off = 32; off > 0; off >>= 1) a += __shfl_down(a, off, 64);
    __shared__ float wpart[4];
    const int lane = threadIdx.x & 63, wid = threadIdx.x >> 6;
    if (lane == 0) wpart[wid] = a;
    __syncthreads();
    if (threadIdx.x == 0)
        t_part[blockIdx.x] = wpart[0] + wpart[1] + wpart[2] + wpart[3];
}

__global__ __launch_bounds__(BT) void pairs_kernel(
    const float4* __restrict__ p4, int T, int Tj,
    float* __restrict__ partials)
{
    // decode linear block id -> (ti, js): js in [ti/2, Tj)
    const int b = blockIdx.x;
    // continuous guess: ti*Tj - ti^2/4 = b  ->  ti = 2*Tj - sqrt(4Tj^2 - 4b)
    float arg = (float)(4 * Tj * Tj - 4 * b);
    arg = arg > 0.0f ? arg : 0.0f;
    int ti = (int)(2.0f * (float)Tj - sqrtf(arg));
    if (ti < 0) ti = 0;
    if (ti > T - 1) ti = T - 1;
    while (ti > 0 && row_off(ti, Tj) > b) --ti;
    while (row_off(ti + 1, Tj) <= b) ++ti;
    const int js = (ti >> 1) + (b - row_off(ti, Tj));

    __shared__ float4 qs[TJ];
    if (threadIdx.x < TJ) qs[threadIdx.x] = p4[js * TJ + threadIdx.x];
    __syncthreads();

    const int lane = threadIdx.x & 63, wid = threadIdx.x >> 6;
    // waves 0,1 own tj = 2js (q[0:64)); waves 2,3 own tj = 2js+1 (q[64:128))
    const int tj = 2 * js + (wid >> 1);
    const float w = (tj < ti) ? 0.0f : ((tj == ti) ? 0.5f : 1.0f);

    float part = 0.0f;
    if (w != 0.0f) {                         // wave-uniform skip
        const float4 P = p4[ti * TI + lane]; // coalesced, L2-hot
        const float pai = P.z * P.w;         // quarter-area
        const int qoff = (wid & 1) * 32 + (wid >> 1) * 64;
        float a0 = 0.0f, a1 = 0.0f;
        #pragma unroll
        for (int k = 0; k < 32; k += 2) {
            a0 += term(P, pai, qs[qoff + k]);
            a1 += term(P, pai, qs[qoff + k + 1]);
        }
        part = (a0 + a1) * w;
    }

    for (int off = 32; off > 0; off >>= 1) part += __shfl_down(part, off, 64);
    if (lane == 0) partials[b * 4 + wid] = part;     // per-wave partial
}

__global__ __launch_bounds__(256) void fin_kernel(
    const float* __restrict__ partials, int np,
    const float* __restrict__ t_part, int nt, float* __restrict__ out)
{
    float s = 0.0f;
    for (int i = threadIdx.x; i < np; i += 256) s += partials[i];
    float t = 0.0f;
    for (int i = threadIdx.x; i < nt; i += 256) t += t_part[i];
    for (int off = 32; off > 0; off >>= 1) {
        s += __shfl_down(s, off, 64);
        t += __shfl_down(t, off, 64);
    }
    __shared__ float ws[4], wt[4];
    const int lane = threadIdx.x & 63, wid = threadIdx.x >> 6;
    if (lane == 0) { ws[wid] = s; wt[wid] = t; }
    __syncthreads();
    if (threadIdx.x == 0) {
        float S = ws[0] + ws[1] + ws[2] + ws[3];
        float T = wt[0] + wt[1] + wt[2] + wt[3];
        // quarter-area scale: triu = 4*S - T
        float l = (4.0f * S - T) / T;
        out[0] = l * l;
    }
}

extern "C" void kernel_launch(void* const* d_in, const int* in_sizes, int n_in,
                              void* d_out, int out_size, void* d_ws, size_t ws_size,
                              hipStream_t stream) {
    const float* pos = (const float*)d_in[0];
    const float* msx = (const float*)d_in[1];
    const float* msy = (const float*)d_in[2];
    const float* bpx = (const float*)d_in[3];
    const float* bpy = (const float*)d_in[4];
    const int*  midx = (const int*)d_in[5];

    const int num_nodes = in_sizes[0] / 2;
    const int m  = in_sizes[5];          // 4000 movable macros
    const int nb = in_sizes[3];          // 252 boundary nodes
    const int N  = m + nb;

    const int T     = (N + TI - 1) / TI;     // 68 i-tiles
    const int Tj    = (T + 1) / 2;           // 34 j-slabs of 128
    const int Npad  = Tj * TJ;               // 4352
    const int nblk  = row_off(T, Tj);        // 1190 (ti, js) blocks
    const int nprep = (Npad + 255) / 256;    // 17

    float4* p4       = (float4*)d_ws;
    float*  t_part   = (float*)(p4 + Npad);
    float*  partials = t_part + nprep;       // 4 * nblk floats

    prep_kernel<<<nprep, 256, 0, stream>>>(pos, msx, msy, bpx, bpy, midx,
                                           num_nodes, m, N, Npad, p4, t_part);

    pairs_kernel<<<nblk, BT, 0, stream>>>(p4, T, Tj, partials);

    fin_kernel<<<1, 256, 0, stream>>>(partials, 4 * nblk, t_part, nprep,
                                      (float*)d_out);
}